// Round 11
// baseline (142.938 us; speedup 1.0000x reference)
//
#include <hip/hip_runtime.h>
#include <hip/hip_bf16.h>
#include <math.h>

#define HDIM 2048
#define KDIM 2048
#define SDIM 8192
#define VDIM 2048
#define BKT  32
#define NT   (KDIM / BKT)   // 64 K-tiles
#define BUFSZ 32768         // 16KB A + 16KB B per K-tile buffer
#define RING  98304         // 3 buffers

using short8 = __attribute__((ext_vector_type(8))) short;
using f32x4  = __attribute__((ext_vector_type(4))) float;
using us8    = __attribute__((ext_vector_type(8))) unsigned short;

typedef const __attribute__((address_space(1))) void g_void;
typedef __attribute__((address_space(3))) void lds_void;

__device__ __forceinline__ unsigned short f2bf(float f) {
  union { float f; unsigned int u; } x; x.f = f;
  unsigned int r = x.u + 0x7fffu + ((x.u >> 16) & 1u);  // RNE
  return (unsigned short)(r >> 16);
}

__device__ __forceinline__ float tanh_fast(float x) {
  float e = __expf(2.0f * x);
  return 1.0f - 2.0f * __builtin_amdgcn_rcpf(e + 1.0f);
}

__device__ __forceinline__ void barrier_sync() {
  asm volatile("" ::: "memory");
  __builtin_amdgcn_s_barrier();
  asm volatile("" ::: "memory");
}

// ------- kernel A: fused f32->bf16 convert (key,Wk) + pq projection -------
__global__ __launch_bounds__(256) void cvt_pq_kernel(const float* __restrict__ key,
                                                     const float* __restrict__ Wk,
                                                     unsigned short* __restrict__ outbf,
                                                     const float* __restrict__ query,
                                                     const float* __restrict__ Wq,
                                                     float* __restrict__ pq,
                                                     int keyN8, int cvtBlocks) {
  if ((int)blockIdx.x < cvtBlocks) {
    int i = blockIdx.x * 256 + threadIdx.x;
    const float* src = (i < keyN8) ? &key[(size_t)i * 8] : &Wk[((size_t)i - keyN8) * 8];
    f32x4 a = *(const f32x4*)src;
    f32x4 b = *(const f32x4*)(src + 4);
    us8 o;
    #pragma unroll
    for (int j = 0; j < 4; ++j) { o[j] = f2bf(a[j]); o[j + 4] = f2bf(b[j]); }
    *(us8*)&outbf[(size_t)i * 8] = o;
  } else {
    int wave = threadIdx.x >> 6, lane = threadIdx.x & 63;
    int h = (blockIdx.x - cvtBlocks) * 4 + wave;
    const float* w = Wq + (size_t)h * KDIM;
    f32x4 s4 = (f32x4)(0.0f);
    #pragma unroll
    for (int i = 0; i < KDIM / 256; ++i) {
      f32x4 q4 = *(const f32x4*)&query[lane * 4 + i * 256];
      f32x4 w4 = *(const f32x4*)&w[lane * 4 + i * 256];
      #pragma unroll
      for (int j = 0; j < 4; ++j) s4[j] = fmaf(q4[j], w4[j], s4[j]);
    }
    float s = s4[0] + s4[1] + s4[2] + s4[3];
    #pragma unroll
    for (int off = 32; off; off >>= 1) s += __shfl_xor(s, off);
    if (lane == 0) pq[h] = s;
  }
}

// ---- kernel B: fused scores. 256x256 tile, 8 waves (2x4), BK=32 ----
// 3-buffer LDS ring (depth-2 DMA prefetch, counted vmcnt(4) only) +
// 2 phases/K-tile: {reads + 2 stage-ops | barrier | setprio+16 MFMA | barrier}.
// Swizzle on 64B rows: 16B-chunk ^= (row>>1)&3 (stage source pre-applies it).
__global__ __launch_bounds__(512, 2) void scores_kernel(const unsigned short* __restrict__ keybf,
                                                        const unsigned short* __restrict__ wkbf,
                                                        const float* __restrict__ pq,
                                                        const float* __restrict__ Ws,
                                                        float* __restrict__ partial) {
  __shared__ unsigned short lds[RING / 2];   // 96 KiB

  const int tid = threadIdx.x;
  // bijective XCD swizzle: XCD g gets 4 consecutive s-tiles x all 8 h-tiles
  const int bid = blockIdx.x;
  const int xg = bid & 7, xi = bid >> 3;
  const int bx = xg * 4 + (xi & 3);      // s-tile 0..31
  const int by = xi >> 2;                // h-tile 0..7
  const int s0 = bx * 256, h0 = by * 256;

  const int wave = tid >> 6, lane = tid & 63;
  const int wm = wave >> 2, wn = wave & 3;     // 2 x 4 waves; wave tile 128(s) x 64(h)
  const int l16 = lane & 15, g16 = lane >> 4;

  // ---- staging map: op = 128 rows x 64B; thread t -> row t>>2, 16B chunk (t&3)^((t>>3)&3) ----
  const int srow = tid >> 2;                               // 0..127 within op
  const int schunk = (tid & 3) ^ ((tid >> 3) & 3);         // inverse-swizzled source chunk
  const char* aSrc0 = (const char*)keybf + ((size_t)(s0 + srow) * KDIM) * 2 + schunk * 16;
  const char* bSrc0 = (const char*)wkbf  + ((size_t)(h0 + srow) * KDIM) * 2 + schunk * 16;

  // op o covers tile rows o*128..o*128+127; wave w writes rows o*128+w*16..+15 (1KB)
  #define STAGE_A(o, kt, nb) __builtin_amdgcn_global_load_lds( \
      (g_void*)(aSrc0 + (size_t)(o) * 128 * KDIM * 2 + (size_t)(kt) * 64), \
      (lds_void*)((char*)lds + (nb) + (o) * 8192 + wave * 1024), 16, 0, 0)
  #define STAGE_B(o, kt, nb) __builtin_amdgcn_global_load_lds( \
      (g_void*)(bSrc0 + (size_t)(o) * 128 * KDIM * 2 + (size_t)(kt) * 64), \
      (lds_void*)((char*)lds + (nb) + 16384 + (o) * 8192 + wave * 1024), 16, 0, 0)

  // ---- read-side: row r at byte r*64, chunk g16 ^ ((r>>1)&3); (r>>1)&3 == (l16>>1)&3 ----
  const int colx = (g16 * 16) ^ (((l16 >> 1) & 3) << 4);
  const int aRowBase = (wm * 128 + l16) * 64;           // + m*1024
  const int bRowBase = 16384 + (wn * 64 + l16) * 64;    // + n*1024

  f32x4 acc[8][4];
  #pragma unroll
  for (int m = 0; m < 8; ++m)
    #pragma unroll
    for (int n = 0; n < 4; ++n) acc[m][n] = (f32x4)(0.0f);

  // ---- prologue: stage tiles 0 (buf0) and 1 (buf1) ----
  STAGE_A(0, 0, 0); STAGE_A(1, 0, 0); STAGE_B(0, 0, 0); STAGE_B(1, 0, 0);
  STAGE_A(0, 1, BUFSZ); STAGE_A(1, 1, BUFSZ); STAGE_B(0, 1, BUFSZ); STAGE_B(1, 1, BUFSZ);
  asm volatile("s_waitcnt vmcnt(4)" ::: "memory");   // tile 0 landed; tile 1 in flight
  barrier_sync();

  int cb = 0;   // current buffer byte offset

  short8 a_[4], b_[4];

  for (int t = 0; t < NT; ++t) {
    int nb = cb + 2 * BUFSZ; if (nb >= RING) nb -= RING;
    const bool more2 = (t + 2 < NT);

    // ===== phase 0: read a0-3 + b0-3; stage A-ops of tile t+2; MFMA m0-3 x n0-3 =====
    #pragma unroll
    for (int m = 0; m < 4; ++m)
      a_[m] = *(const short8*)((const char*)lds + cb + aRowBase + m * 1024 + colx);
    #pragma unroll
    for (int n = 0; n < 4; ++n)
      b_[n] = *(const short8*)((const char*)lds + cb + bRowBase + n * 1024 + colx);
    if (more2) { STAGE_A(0, t + 2, nb); STAGE_A(1, t + 2, nb); }
    barrier_sync();
    __builtin_amdgcn_s_setprio(1);
    #pragma unroll
    for (int m = 0; m < 4; ++m)
      #pragma unroll
      for (int n = 0; n < 4; ++n)
        acc[m][n] = __builtin_amdgcn_mfma_f32_16x16x32_bf16(a_[m], b_[n], acc[m][n], 0, 0, 0);
    __builtin_amdgcn_s_setprio(0);
    barrier_sync();

    // ===== phase 1: read a4-7; stage B-ops of tile t+2; MFMA m4-7 x n0-3 =====
    #pragma unroll
    for (int m = 0; m < 4; ++m)
      a_[m] = *(const short8*)((const char*)lds + cb + aRowBase + (m + 4) * 1024 + colx);
    if (more2) { STAGE_B(0, t + 2, nb); STAGE_B(1, t + 2, nb); }
    barrier_sync();
    __builtin_amdgcn_s_setprio(1);
    #pragma unroll
    for (int m = 0; m < 4; ++m)
      #pragma unroll
      for (int n = 0; n < 4; ++n)
        acc[m + 4][n] = __builtin_amdgcn_mfma_f32_16x16x32_bf16(a_[m], b_[n], acc[m + 4][n], 0, 0, 0);
    __builtin_amdgcn_s_setprio(0);
    // counted wait: all but newest 4 DMAs done => tile t+1 fully landed
    if (more2)
      asm volatile("s_waitcnt vmcnt(4)" ::: "memory");
    else
      asm volatile("s_waitcnt vmcnt(0)" ::: "memory");
    barrier_sync();

    cb += BUFSZ; if (cb >= RING) cb = 0;
  }

  // ---- epilogue: h = h0 + wn*64 + n*16 + l16 ; s = s0 + wm*128 + m*16 + g16*4 + j
  float pqv[4], wsv[4];
  #pragma unroll
  for (int n = 0; n < 4; ++n) {
    int h = h0 + wn * 64 + n * 16 + l16;
    pqv[n] = pq[h];
    wsv[n] = Ws[h];
  }

  float* sred = (float*)lds;   // [256][4] overlay (4KB)
  #pragma unroll
  for (int m = 0; m < 8; ++m) {
    #pragma unroll
    for (int j = 0; j < 4; ++j) {
      float rs = 0.f;
      #pragma unroll
      for (int n = 0; n < 4; ++n)
        rs += tanh_fast(acc[m][n][j] + pqv[n]) * wsv[n];
      rs += __shfl_xor(rs, 1);
      rs += __shfl_xor(rs, 2);
      rs += __shfl_xor(rs, 4);
      rs += __shfl_xor(rs, 8);
      if (l16 == 0)
        sred[(wm * 128 + m * 16 + g16 * 4 + j) * 4 + wn] = rs;
    }
  }
  __syncthreads();
  if (tid < 256) {
    float v = sred[tid * 4 + 0] + sred[tid * 4 + 1] + sred[tid * 4 + 2] + sred[tid * 4 + 3];
    partial[(size_t)(s0 + tid) * 8 + by] = v;
  }
}

// ---------------- kernel 3: softmax over S=8192 (single block) ----------------
__global__ __launch_bounds__(1024) void softmax_kernel(const float* __restrict__ partial,
                                                       float* __restrict__ weights) {
  __shared__ float red[16];
  int tid = threadIdx.x;
  int sbase = tid * 8;
  float sc[8];
  float mx = -1e30f;
  #pragma unroll
  for (int i = 0; i < 8; ++i) {
    const float* p = partial + (size_t)(sbase + i) * 8;
    float v = 0.f;
    #pragma unroll
    for (int q = 0; q < 8; ++q) v += p[q];
    sc[i] = v;
    mx = fmaxf(mx, v);
  }
  #pragma unroll
  for (int off = 32; off; off >>= 1) mx = fmaxf(mx, __shfl_xor(mx, off));
  if ((tid & 63) == 0) red[tid >> 6] = mx;
  __syncthreads();
  float gmx = red[0];
  #pragma unroll
  for (int q = 1; q < 16; ++q) gmx = fmaxf(gmx, red[q]);
  __syncthreads();
  float ls = 0.f;
  #pragma unroll
  for (int i = 0; i < 8; ++i) { sc[i] = expf(sc[i] - gmx); ls += sc[i]; }
  #pragma unroll
  for (int off = 32; off; off >>= 1) ls += __shfl_xor(ls, off);
  if ((tid & 63) == 0) red[tid >> 6] = ls;
  __syncthreads();
  float gs = 0.f;
  #pragma unroll
  for (int q = 0; q < 16; ++q) gs += red[q];
  float inv = 1.0f / gs;
  #pragma unroll
  for (int i = 0; i < 8; ++i) weights[sbase + i] = sc[i] * inv;
}

// ---------------- kernel 4: context partials (float4, 64-row chunks) ----------------
__global__ __launch_bounds__(256) void ctx_partial_kernel(const float* __restrict__ values,
                                                          const float* __restrict__ w,
                                                          float* __restrict__ part) {
  int vcol4 = blockIdx.x * 256 + threadIdx.x;
  int ss0 = blockIdx.y * 64;
  f32x4 acc = (f32x4)(0.0f);
  for (int s = ss0; s < ss0 + 64; ++s) {
    f32x4 v = *(const f32x4*)&values[(size_t)s * VDIM + vcol4 * 4];
    float ws = w[s];
    #pragma unroll
    for (int j = 0; j < 4; ++j) acc[j] = fmaf(ws, v[j], acc[j]);
  }
  *(f32x4*)&part[(size_t)blockIdx.y * VDIM + vcol4 * 4] = acc;
}

// ---------------- kernel 5: context reduce ----------------
__global__ __launch_bounds__(256) void ctx_reduce_kernel(const float* __restrict__ part,
                                                         float* __restrict__ ctx) {
  int vcol = blockIdx.x * 256 + threadIdx.x;
  float acc = 0.f;
  #pragma unroll
  for (int p = 0; p < 128; ++p) acc += part[(size_t)p * VDIM + vcol];
  ctx[vcol] = acc;
}

extern "C" void kernel_launch(void* const* d_in, const int* in_sizes, int n_in,
                              void* d_out, int out_size, void* d_ws, size_t ws_size,
                              hipStream_t stream) {
  const float* query  = (const float*)d_in[0];
  const float* key    = (const float*)d_in[1];
  const float* values = (const float*)d_in[2];
  const float* Wq     = (const float*)d_in[3];
  const float* Wk     = (const float*)d_in[4];
  const float* Ws     = (const float*)d_in[5];

  float* out     = (float*)d_out;
  float* weights = out;          // [8192]
  float* ctx     = out + SDIM;   // [2048]

  char* ws = (char*)d_ws;
  unsigned short* keybf = (unsigned short*)ws;                              // 32 MiB
  unsigned short* wkbf  = (unsigned short*)(ws + (size_t)SDIM * KDIM * 2);  // 8 MiB
  char* tail = ws + (size_t)SDIM * KDIM * 2 + (size_t)HDIM * KDIM * 2;
  float* pq      = (float*)tail;                          // 2048 f32
  float* partial = (float*)(tail + 8192);                 // 8192*8 f32 (256 KiB)
  float* cpart   = (float*)(tail + 8192 + (size_t)SDIM * 8 * 4);  // 128*2048 f32 (1 MiB)

  const int keyN8 = SDIM * KDIM / 8;
  const int totN8 = keyN8 + HDIM * KDIM / 8;
  const int cvtBlocks = totN8 / 256;   // 10240 (exact)
  cvt_pq_kernel<<<cvtBlocks + HDIM / 4, 256, 0, stream>>>(key, Wk, keybf, query, Wq, pq,
                                                          keyN8, cvtBlocks);
  scores_kernel<<<256, 512, 0, stream>>>(keybf, wkbf, pq, Ws, partial);
  softmax_kernel<<<1, 1024, 0, stream>>>(partial, weights);
  ctx_partial_kernel<<<dim3(VDIM / (256 * 4), 128), 256, 0, stream>>>(values, weights, cpart);
  ctx_reduce_kernel<<<VDIM / 256, 256, 0, stream>>>(cpart, ctx);
}

// Round 12
// 126.560 us; speedup vs baseline: 1.1294x; 1.1294x over previous
//
#include <hip/hip_runtime.h>
#include <hip/hip_bf16.h>
#include <math.h>

#define HDIM 2048
#define KDIM 2048
#define SDIM 8192
#define VDIM 2048
#define BKT  64
#define NT   (KDIM / BKT)   // 32 K-tiles

using short8 = __attribute__((ext_vector_type(8))) short;
using f32x4  = __attribute__((ext_vector_type(4))) float;
using us8    = __attribute__((ext_vector_type(8))) unsigned short;

typedef const __attribute__((address_space(1))) void g_void;
typedef __attribute__((address_space(3))) void lds_void;

__device__ __forceinline__ unsigned short f2bf(float f) {
  union { float f; unsigned int u; } x; x.f = f;
  unsigned int r = x.u + 0x7fffu + ((x.u >> 16) & 1u);  // RNE
  return (unsigned short)(r >> 16);
}

__device__ __forceinline__ float tanh_fast(float x) {
  float e = __expf(2.0f * x);
  return 1.0f - 2.0f * __builtin_amdgcn_rcpf(e + 1.0f);
}

__device__ __forceinline__ void barrier_sync() {
  asm volatile("" ::: "memory");
  __builtin_amdgcn_s_barrier();
  asm volatile("" ::: "memory");
}

// ------- kernel A: fused f32->bf16 convert (key,Wk) + pq projection -------
__global__ __launch_bounds__(256) void cvt_pq_kernel(const float* __restrict__ key,
                                                     const float* __restrict__ Wk,
                                                     unsigned short* __restrict__ outbf,
                                                     const float* __restrict__ query,
                                                     const float* __restrict__ Wq,
                                                     float* __restrict__ pq,
                                                     int keyN8, int cvtBlocks) {
  if ((int)blockIdx.x < cvtBlocks) {
    int i = blockIdx.x * 256 + threadIdx.x;
    const float* src = (i < keyN8) ? &key[(size_t)i * 8] : &Wk[((size_t)i - keyN8) * 8];
    f32x4 a = __builtin_nontemporal_load((const f32x4*)src);
    f32x4 b = __builtin_nontemporal_load((const f32x4*)(src + 4));
    us8 o;
    #pragma unroll
    for (int j = 0; j < 4; ++j) { o[j] = f2bf(a[j]); o[j + 4] = f2bf(b[j]); }
    *(us8*)&outbf[(size_t)i * 8] = o;
  } else {
    int wave = threadIdx.x >> 6, lane = threadIdx.x & 63;
    int h = (blockIdx.x - cvtBlocks) * 4 + wave;
    const float* w = Wq + (size_t)h * KDIM;
    f32x4 s4 = (f32x4)(0.0f);
    #pragma unroll
    for (int i = 0; i < KDIM / 256; ++i) {
      f32x4 q4 = *(const f32x4*)&query[lane * 4 + i * 256];
      f32x4 w4 = __builtin_nontemporal_load((const f32x4*)&w[lane * 4 + i * 256]);
      #pragma unroll
      for (int j = 0; j < 4; ++j) s4[j] = fmaf(q4[j], w4[j], s4[j]);
    }
    float s = s4[0] + s4[1] + s4[2] + s4[3];
    #pragma unroll
    for (int off = 32; off; off >>= 1) s += __shfl_xor(s, off);
    if (lane == 0) pq[h] = s;
  }
}

// ---- kernel B: fused scores (exact R10 structure — measured best, 77.5us) ----
// 256x256 tile, 8 waves (2x4), BK=64, single barrier per K-tile, 2-buffer LDS,
// XOR-swizzled rows, ks-outer MFMA, setprio around MFMA bursts.
__global__ __launch_bounds__(512, 2) void scores_kernel(const unsigned short* __restrict__ keybf,
                                                        const unsigned short* __restrict__ wkbf,
                                                        const float* __restrict__ pq,
                                                        const float* __restrict__ Ws,
                                                        float* __restrict__ partial) {
  __shared__ unsigned short lds[65536];   // 128 KiB

  const int tid = threadIdx.x;
  const int bid = blockIdx.x;
  const int xg = bid & 7, xi = bid >> 3;
  const int bx = xg * 4 + (xi & 3);      // s-tile 0..31
  const int by = xi >> 2;                // h-tile 0..7
  const int s0 = bx * 256, h0 = by * 256;

  const int wave = tid >> 6, lane = tid & 63;
  const int wm = wave >> 2, wn = wave & 3;     // 2 x 4 waves; wave tile 128(s) x 64(h)
  const int l16 = lane & 15, g16 = lane >> 4;

  const int srow = tid >> 3;
  const int scol = ((tid & 7) * 16) ^ ((srow & 7) << 4);   // inverse-swizzled source col
  const char* aSrc0 = (const char*)keybf + ((size_t)(s0 + srow) * KDIM) * 2 + scol;
  const char* bSrc0 = (const char*)wkbf  + ((size_t)(h0 + srow) * KDIM) * 2 + scol;

  #define STAGE_A(o, kt, buf) __builtin_amdgcn_global_load_lds( \
      (g_void*)(aSrc0 + (size_t)(o) * 64 * KDIM * 2 + (size_t)(kt) * 128), \
      (lds_void*)((char*)lds + (size_t)(buf) * 65536 + (o) * 8192 + wave * 1024), 16, 0, 0)
  #define STAGE_B(o, kt, buf) __builtin_amdgcn_global_load_lds( \
      (g_void*)(bSrc0 + (size_t)(o) * 64 * KDIM * 2 + (size_t)(kt) * 128), \
      (lds_void*)((char*)lds + (size_t)(buf) * 65536 + 32768 + (o) * 8192 + wave * 1024), 16, 0, 0)

  const int xorv = (l16 & 7) << 4;
  int colx[2];
  colx[0] = ((g16 * 16)      ) ^ xorv;
  colx[1] = ((g16 * 16) | 64 ) ^ xorv;
  const int aRowBase = (wm * 128 + l16) * 128;        // + m*2048
  const int bRowBase = 32768 + (wn * 64 + l16) * 128; // + n*2048

  f32x4 acc[8][4];
  #pragma unroll
  for (int m = 0; m < 8; ++m)
    #pragma unroll
    for (int n = 0; n < 4; ++n) acc[m][n] = (f32x4)(0.0f);

  STAGE_A(0, 0, 0); STAGE_A(1, 0, 0); STAGE_A(2, 0, 0); STAGE_A(3, 0, 0);
  STAGE_B(0, 0, 0); STAGE_B(1, 0, 0); STAGE_B(2, 0, 0); STAGE_B(3, 0, 0);
  asm volatile("s_waitcnt vmcnt(0)" ::: "memory");
  barrier_sync();

  short8 af[4][2], bf_[4][2];

  for (int t = 0; t < NT; ++t) {
    const int cbase = (t & 1) * 65536;
    const int nbuf = (t & 1) ^ 1;
    const bool more = (t + 1 < NT);

    #pragma unroll
    for (int m = 0; m < 4; ++m)
      #pragma unroll
      for (int ks = 0; ks < 2; ++ks)
        af[m][ks] = *(const short8*)((const char*)lds + cbase + aRowBase + m * 2048 + colx[ks]);
    #pragma unroll
    for (int n = 0; n < 4; ++n)
      #pragma unroll
      for (int ks = 0; ks < 2; ++ks)
        bf_[n][ks] = *(const short8*)((const char*)lds + cbase + bRowBase + n * 2048 + colx[ks]);

    if (more) {
      STAGE_A(0, t + 1, nbuf); STAGE_A(1, t + 1, nbuf);
      STAGE_A(2, t + 1, nbuf); STAGE_A(3, t + 1, nbuf);
      STAGE_B(0, t + 1, nbuf); STAGE_B(1, t + 1, nbuf);
      STAGE_B(2, t + 1, nbuf); STAGE_B(3, t + 1, nbuf);
    }

    __builtin_amdgcn_s_setprio(1);
    #pragma unroll
    for (int ks = 0; ks < 2; ++ks)
      #pragma unroll
      for (int m = 0; m < 4; ++m)
        #pragma unroll
        for (int n = 0; n < 4; ++n)
          acc[m][n] = __builtin_amdgcn_mfma_f32_16x16x32_bf16(af[m][ks], bf_[n][ks], acc[m][n], 0, 0, 0);
    __builtin_amdgcn_s_setprio(0);

    #pragma unroll
    for (int m = 0; m < 4; ++m)
      #pragma unroll
      for (int ks = 0; ks < 2; ++ks)
        af[m][ks] = *(const short8*)((const char*)lds + cbase + aRowBase + (m + 4) * 2048 + colx[ks]);

    __builtin_amdgcn_s_setprio(1);
    #pragma unroll
    for (int ks = 0; ks < 2; ++ks)
      #pragma unroll
      for (int m = 0; m < 4; ++m)
        #pragma unroll
        for (int n = 0; n < 4; ++n)
          acc[m + 4][n] = __builtin_amdgcn_mfma_f32_16x16x32_bf16(af[m][ks], bf_[n][ks], acc[m + 4][n], 0, 0, 0);
    __builtin_amdgcn_s_setprio(0);

    asm volatile("s_waitcnt vmcnt(0)" ::: "memory");
    barrier_sync();
  }

  float pqv[4], wsv[4];
  #pragma unroll
  for (int n = 0; n < 4; ++n) {
    int h = h0 + wn * 64 + n * 16 + l16;
    pqv[n] = pq[h];
    wsv[n] = Ws[h];
  }

  float* sred = (float*)lds;   // [256][4] overlay
  #pragma unroll
  for (int m = 0; m < 8; ++m) {
    #pragma unroll
    for (int j = 0; j < 4; ++j) {
      float rs = 0.f;
      #pragma unroll
      for (int n = 0; n < 4; ++n)
        rs += tanh_fast(acc[m][n][j] + pqv[n]) * wsv[n];
      rs += __shfl_xor(rs, 1);
      rs += __shfl_xor(rs, 2);
      rs += __shfl_xor(rs, 4);
      rs += __shfl_xor(rs, 8);
      if (l16 == 0)
        sred[(wm * 128 + m * 16 + g16 * 4 + j) * 4 + wn] = rs;
    }
  }
  __syncthreads();
  if (tid < 256) {
    float v = sred[tid * 4 + 0] + sred[tid * 4 + 1] + sred[tid * 4 + 2] + sred[tid * 4 + 3];
    partial[(size_t)(s0 + tid) * 8 + by] = v;
  }
}

// ---- kernel C: per-chunk softmax partials. 32 blocks x 256 s-rows ----
// writes wexp[s] = exp(sc[s]-lmax_b) and pairs[b] = (lmax_b, lsum_b)
__global__ __launch_bounds__(256) void smax_part_kernel(const float* __restrict__ partial,
                                                        float* __restrict__ wexp,
                                                        float* __restrict__ pairs) {
  __shared__ float red[8];
  int tid = threadIdx.x, wave = tid >> 6, lane = tid & 63;
  int s = blockIdx.x * 256 + tid;
  const float* p = partial + (size_t)s * 8;
  float v = 0.f;
  #pragma unroll
  for (int q = 0; q < 8; ++q) v += p[q];
  float mx = v;
  #pragma unroll
  for (int off = 32; off; off >>= 1) mx = fmaxf(mx, __shfl_xor(mx, off));
  if (lane == 0) red[wave] = mx;
  __syncthreads();
  float bmax = fmaxf(fmaxf(red[0], red[1]), fmaxf(red[2], red[3]));
  float e = __expf(v - bmax);
  wexp[s] = e;
  float sm = e;
  #pragma unroll
  for (int off = 32; off; off >>= 1) sm += __shfl_xor(sm, off);
  if (lane == 0) red[4 + wave] = sm;
  __syncthreads();
  if (tid == 0)
    { pairs[blockIdx.x * 2] = bmax; pairs[blockIdx.x * 2 + 1] = red[4] + red[5] + red[6] + red[7]; }
}

// ---- kernel D: fused global-softmax finish + weights write + context ----
// 256 blocks; each: redundant 32-pair global max/sum, 8 v-cols over full S,
// in-block tree reduce. blocks 0..31 also write the weights output chunk.
__global__ __launch_bounds__(256) void ctx_fused_kernel(const float* __restrict__ values,
                                                        const float* __restrict__ wexp,
                                                        const float* __restrict__ pairs,
                                                        float* __restrict__ weights,
                                                        float* __restrict__ ctx) {
  __shared__ float scl[32];
  __shared__ f32x4 sred[256];
  int tid = threadIdx.x, b = blockIdx.x;

  float gmax = -1e30f;
  #pragma unroll
  for (int i = 0; i < 32; ++i) gmax = fmaxf(gmax, pairs[2 * i]);
  float gs = 0.f;
  #pragma unroll
  for (int i = 0; i < 32; ++i) gs += pairs[2 * i + 1] * __expf(pairs[2 * i] - gmax);
  if (tid < 32) scl[tid] = __expf(pairs[2 * tid] - gmax);
  __syncthreads();
  float inv = 1.0f / gs;

  if (b < 32) {
    int s = b * 256 + tid;
    weights[s] = wexp[s] * scl[b] * inv;
  }

  const int c4 = b * 2 + (tid & 1);    // float4 column index (8 cols per block)
  const int g  = tid >> 1;             // 128 s-groups
  f32x4 acc = (f32x4)(0.0f);
  for (int s = g; s < SDIM; s += 128) {
    float w = wexp[s] * scl[s >> 8];
    f32x4 v = *(const f32x4*)&values[(size_t)s * VDIM + c4 * 4];
    #pragma unroll
    for (int j = 0; j < 4; ++j) acc[j] = fmaf(w, v[j], acc[j]);
  }
  sred[tid] = acc;
  #pragma unroll
  for (int step = 64; step; step >>= 1) {
    __syncthreads();
    if (g < step) {
      f32x4 a = sred[tid], o = sred[tid + step * 2];
      #pragma unroll
      for (int j = 0; j < 4; ++j) a[j] += o[j];
      sred[tid] = a;
    }
  }
  __syncthreads();
  if (tid < 2) {
    f32x4 a = sred[tid];
    #pragma unroll
    for (int j = 0; j < 4; ++j) a[j] *= inv;
    *(f32x4*)&ctx[(size_t)(b * 2 + tid) * 4] = a;
  }
}

extern "C" void kernel_launch(void* const* d_in, const int* in_sizes, int n_in,
                              void* d_out, int out_size, void* d_ws, size_t ws_size,
                              hipStream_t stream) {
  const float* query  = (const float*)d_in[0];
  const float* key    = (const float*)d_in[1];
  const float* values = (const float*)d_in[2];
  const float* Wq     = (const float*)d_in[3];
  const float* Wk     = (const float*)d_in[4];
  const float* Ws     = (const float*)d_in[5];

  float* out     = (float*)d_out;
  float* weights = out;          // [8192]
  float* ctx     = out + SDIM;   // [2048]

  char* ws = (char*)d_ws;
  unsigned short* keybf = (unsigned short*)ws;                              // 32 MiB
  unsigned short* wkbf  = (unsigned short*)(ws + (size_t)SDIM * KDIM * 2);  // 8 MiB
  char* tail = ws + (size_t)SDIM * KDIM * 2 + (size_t)HDIM * KDIM * 2;
  float* pq      = (float*)tail;                           // 2048 f32
  float* partial = (float*)(tail + 8192);                  // 8192*8 f32 (256 KiB)
  float* wexp    = (float*)(tail + 8192 + (size_t)SDIM * 8 * 4);   // 8192 f32
  float* pairs   = wexp + SDIM;                            // 64 f32

  const int keyN8 = SDIM * KDIM / 8;
  const int totN8 = keyN8 + HDIM * KDIM / 8;
  const int cvtBlocks = totN8 / 256;   // 10240 (exact)
  cvt_pq_kernel<<<cvtBlocks + HDIM / 4, 256, 0, stream>>>(key, Wk, keybf, query, Wq, pq,
                                                          keyN8, cvtBlocks);
  scores_kernel<<<256, 512, 0, stream>>>(keybf, wkbf, pq, Ws, partial);
  smax_part_kernel<<<32, 256, 0, stream>>>(partial, wexp, pairs);
  ctx_fused_kernel<<<256, 256, 0, stream>>>(values, wexp, pairs, weights, ctx);
}